// Round 1
// 1123.807 us; speedup vs baseline: 1.4847x; 1.4847x over previous
//
#include <hip/hip_runtime.h>
#include <cstdint>

// Problem constants
#define M 8192          // B*H*W = 32*16*16
#define N 8192          // N_E
#define KDIM 512        // E_DIM

// Output layout (flat float32, reference return order)
static const size_t OFF_LOSS = 0;
static const size_t OFF_CONTRASTIVE = 1;
static const size_t OFF_KL = 2;
static const size_t OFF_PROB = 3;                                   // 8192*8192
static const size_t OFF_D    = OFF_PROB + (size_t)M * N;            // 67108867
static const size_t OFF_ZQ   = OFF_D + (size_t)M * N;               // 134217731
static const size_t OFF_PERP = OFF_ZQ + (size_t)M * KDIM;           // 138412035
static const size_t OFF_ENC  = OFF_PERP + 1;                        // 138412036
static const size_t OFF_IDX  = OFF_ENC + (size_t)M * N;             // 205520900

typedef _Float16 f16x8 __attribute__((ext_vector_type(8)));
typedef float f32x4 __attribute__((ext_vector_type(4)));

// Power-of-two scales keep fp16 lo-planes out of subnormal-flush range.
// Exact (exponent shift only); folded out in the GEMM epilogue.
#define ZSCALE 16.0f     // z ~ N(0,1): |z*16| <~ 100
#define CSCALE 512.0f    // cb entries ~ +-0.08: |cb*512| <~ 50
#define INV_SCALE (1.0f / (16.0f * 512.0f))   // 2^-13, exact

__device__ __forceinline__ void gload16(const void* g, void* l) {
  __builtin_amdgcn_global_load_lds(
      (const __attribute__((address_space(1))) uint32_t*)g,
      (__attribute__((address_space(3))) uint32_t*)l, 16, 0, 0);
}

// ---------------------------------------------------------------------------
// Kernel 1 (prep): row norms + fp16 hi/lo split of scaled inputs.
// One wave per row; rows 0..8191 = emb (-> cb split), 8192..16383 = z.
// ---------------------------------------------------------------------------
__global__ __launch_bounds__(256) void prep_kernel(
    const float* __restrict__ z, const float* __restrict__ emb,
    float* __restrict__ inv_norm, float* __restrict__ cbn,
    float* __restrict__ zn,
    _Float16* __restrict__ zhi, _Float16* __restrict__ zlo,
    _Float16* __restrict__ chi, _Float16* __restrict__ clo) {
  int g = blockIdx.x * 4 + (threadIdx.x >> 6);
  int lane = threadIdx.x & 63;
  if (g < N) {
    const float* p = emb + (size_t)g * KDIM + lane * 8;
    float4 v0 = *(const float4*)p;
    float4 v1 = *(const float4*)(p + 4);
    float s = v0.x * v0.x + v0.y * v0.y + v0.z * v0.z + v0.w * v0.w +
              v1.x * v1.x + v1.y * v1.y + v1.z * v1.z + v1.w * v1.w;
    #pragma unroll
    for (int off = 32; off > 0; off >>= 1) s += __shfl_down(s, off, 64);
    s = __shfl(s, 0, 64);
    float inv = 1.0f / sqrtf(s);
    float c[8] = {v0.x * inv, v0.y * inv, v0.z * inv, v0.w * inv,
                  v1.x * inv, v1.y * inv, v1.z * inv, v1.w * inv};
    float s2 = 0.0f;
    #pragma unroll
    for (int j = 0; j < 8; j++) s2 += c[j] * c[j];
    #pragma unroll
    for (int off = 32; off > 0; off >>= 1) s2 += __shfl_down(s2, off, 64);
    if (lane == 0) { inv_norm[g] = inv; cbn[g] = sqrtf(s2); }
    f16x8 h, l;
    #pragma unroll
    for (int j = 0; j < 8; j++) {
      float cs = c[j] * CSCALE;
      _Float16 hh = (_Float16)cs;
      h[j] = hh;
      l[j] = (_Float16)(cs - (float)hh);
    }
    *(f16x8*)&chi[(size_t)g * KDIM + lane * 8] = h;
    *(f16x8*)&clo[(size_t)g * KDIM + lane * 8] = l;
  } else {
    int r = g - N;
    const float* p = z + (size_t)r * KDIM + lane * 8;
    float4 v0 = *(const float4*)p;
    float4 v1 = *(const float4*)(p + 4);
    float s = v0.x * v0.x + v0.y * v0.y + v0.z * v0.z + v0.w * v0.w +
              v1.x * v1.x + v1.y * v1.y + v1.z * v1.z + v1.w * v1.w;
    #pragma unroll
    for (int off = 32; off > 0; off >>= 1) s += __shfl_down(s, off, 64);
    if (lane == 0) zn[r] = sqrtf(__shfl(s, 0, 64));
    float c[8] = {v0.x, v0.y, v0.z, v0.w, v1.x, v1.y, v1.z, v1.w};
    f16x8 h, l;
    #pragma unroll
    for (int j = 0; j < 8; j++) {
      float cs = c[j] * ZSCALE;
      _Float16 hh = (_Float16)cs;
      h[j] = hh;
      l[j] = (_Float16)(cs - (float)hh);
    }
    *(f16x8*)&zhi[(size_t)r * KDIM + lane * 8] = h;
    *(f16x8*)&zlo[(size_t)r * KDIM + lane * 8] = l;
  }
}

// ---------------------------------------------------------------------------
// Kernel 2: split-fp16 MFMA GEMM.
//   d[i][j] = (Ah.Bh + Ah.Bl + Al.Bh)[i][j] * 2^-13 / (zn_i*cbn_j + 1e-6)
// 128x128 tile, BK=32, 4 waves (2x2 quadrants of 64x64), 16x16x32_f16 MFMA.
// LDS: [128 rows][64 fp16] per matrix; row = 128B; slots 0-3 = hi k-blocks,
// 4-7 = lo k-blocks; physical slot = logical ^ (row&7) (G4 XOR swizzle).
// global_load_lds writes linearly -> swizzle applied on the SOURCE address
// (rule #21: pre-swizzled source + swizzled read, same involution).
// 2-phase schedule: barrier(drain) -> ds_read frags -> barrier -> STAGE(next)
// -> 48 MFMAs (stage flies under the MFMA cluster).
// ---------------------------------------------------------------------------
__global__ __launch_bounds__(256, 2) void gemm_kernel(
    const _Float16* __restrict__ zhi, const _Float16* __restrict__ zlo,
    const _Float16* __restrict__ chi, const _Float16* __restrict__ clo,
    const float* __restrict__ zn, const float* __restrict__ cbn,
    float* __restrict__ dout) {
  __shared__ __align__(16) _Float16 As[128][64];
  __shared__ __align__(16) _Float16 Bs[128][64];

  const int tid = threadIdx.x;
  const int lane = tid & 63;
  const int wid = tid >> 6;
  const int wr = wid >> 1;        // wave row quadrant (0..1)
  const int wc = wid & 1;         // wave col quadrant (0..1)
  const int l15 = lane & 15;
  const int l4 = lane >> 4;       // 0..3

  // XCD-grouped bijective swizzle over the 64x64 grid (4096 % 8 == 0)
  int bid = blockIdx.y * 64 + blockIdx.x;
  int swz = (bid & 7) * 512 + (bid >> 3);
  const int row0 = (swz >> 6) * 128;
  const int col0 = (swz & 63) * 128;

  // --- staging addresses (per thread, loop-invariant) ---
  // dest byte off (pass p) = p*4096 + tid*16  ->  row = p*32 + tid>>3,
  // physical slot = tid&7. logical slot = physical ^ (row&7); row&7 == srow&7.
  const int srow = tid >> 3;                 // 0..31
  const int sP = tid & 7;
  const int sL = sP ^ (srow & 7);            // logical slot this thread feeds
  const _Float16* asrc = ((sL & 4) ? zlo : zhi) +
                         (size_t)(row0 + srow) * KDIM + (sL & 3) * 8;
  const _Float16* bsrc = ((sL & 4) ? clo : chi) +
                         (size_t)(col0 + srow) * KDIM + (sL & 3) * 8;
  char* adst = (char*)&As[0][0] + tid * 16;
  char* bdst = (char*)&Bs[0][0] + tid * 16;

  f32x4 acc[4][4];
  #pragma unroll
  for (int i = 0; i < 4; i++)
    #pragma unroll
    for (int j = 0; j < 4; j++)
      #pragma unroll
      for (int q = 0; q < 4; q++) acc[i][j][q] = 0.0f;

  auto stage = [&](int kt) {
    #pragma unroll
    for (int p = 0; p < 4; p++) {
      gload16(asrc + (size_t)p * (32 * KDIM) + kt, adst + p * 4096);
      gload16(bsrc + (size_t)p * (32 * KDIM) + kt, bdst + p * 4096);
    }
  };

  stage(0);
  for (int kt = 0; kt < KDIM; kt += 32) {
    __syncthreads();   // drains vmcnt: staged tile visible in LDS

    f16x8 ahi[4], alo[4], bhi[4], blo[4];
    #pragma unroll
    for (int i = 0; i < 4; i++) {
      int ra = wr * 64 + i * 16 + l15;
      int xa = ra & 7;
      ahi[i] = *(const f16x8*)&As[ra][(l4 ^ xa) * 8];
      alo[i] = *(const f16x8*)&As[ra][((l4 + 4) ^ xa) * 8];
      int rb = wc * 64 + i * 16 + l15;
      int xb = rb & 7;
      bhi[i] = *(const f16x8*)&Bs[rb][(l4 ^ xb) * 8];
      blo[i] = *(const f16x8*)&Bs[rb][((l4 + 4) ^ xb) * 8];
    }

    __syncthreads();   // all waves finished reading LDS -> safe to overwrite
    if (kt + 32 < KDIM) stage(kt + 32);   // flies under the MFMA cluster

    #pragma unroll
    for (int m2 = 0; m2 < 4; m2++)
      #pragma unroll
      for (int n2 = 0; n2 < 4; n2++)
        acc[m2][n2] = __builtin_amdgcn_mfma_f32_16x16x32_f16(
            ahi[m2], bhi[n2], acc[m2][n2], 0, 0, 0);
    #pragma unroll
    for (int m2 = 0; m2 < 4; m2++)
      #pragma unroll
      for (int n2 = 0; n2 < 4; n2++)
        acc[m2][n2] = __builtin_amdgcn_mfma_f32_16x16x32_f16(
            ahi[m2], blo[n2], acc[m2][n2], 0, 0, 0);
    #pragma unroll
    for (int m2 = 0; m2 < 4; m2++)
      #pragma unroll
      for (int n2 = 0; n2 < 4; n2++)
        acc[m2][n2] = __builtin_amdgcn_mfma_f32_16x16x32_f16(
            alo[m2], bhi[n2], acc[m2][n2], 0, 0, 0);
  }

  // epilogue: C/D layout col = lane&15, row = (lane>>4)*4 + reg
  const int cb0 = col0 + wc * 64 + l15;
  const int rb0 = row0 + wr * 64 + l4 * 4;
  float cw[4];
  #pragma unroll
  for (int n2 = 0; n2 < 4; n2++) cw[n2] = cbn[cb0 + n2 * 16];
  #pragma unroll
  for (int m2 = 0; m2 < 4; m2++) {
    #pragma unroll
    for (int r2 = 0; r2 < 4; r2++) {
      int row = rb0 + m2 * 16 + r2;
      float zr = zn[row];
      size_t o = (size_t)row * N + cb0;
      #pragma unroll
      for (int n2 = 0; n2 < 4; n2++) {
        dout[o + n2 * 16] =
            (acc[m2][n2][r2] * INV_SCALE) / (zr * cw[n2] + 1e-6f);
      }
    }
  }
}

// ---------------------------------------------------------------------------
// Kernel 3: per-row argmax + softmax + one-hot scatter + z_q gather +
// histogram + cosine accumulation. One 256-thread block per row; the row
// (8192 floats) lives in 32 regs/thread. exp computed ONCE per element.
// ---------------------------------------------------------------------------
__global__ __launch_bounds__(256) void row_kernel(
    const float* __restrict__ dmat, float* __restrict__ prob,
    float* __restrict__ enc, float* __restrict__ zq,
    float* __restrict__ idxout, const float* __restrict__ emb,
    const float* __restrict__ inv_norm, const float* __restrict__ cbn,
    const float* __restrict__ zn, int* __restrict__ counts,
    float* __restrict__ cos_sum) {
  const int row = blockIdx.x;
  const int tid = threadIdx.x;
  const float* drow = dmat + (size_t)row * N;

  float v[32];
  float m = -1e30f;
  int mi = 0;
  #pragma unroll
  for (int u = 0; u < 32; u++) {
    int col = u * 256 + tid;
    float x = drow[col];
    v[u] = x;
    if (x > m) { m = x; mi = col; }   // strict > keeps first occurrence
  }

  __shared__ float sM[256];
  __shared__ int sI[256];
  sM[tid] = m; sI[tid] = mi;
  __syncthreads();
  for (int s = 128; s > 0; s >>= 1) {
    if (tid < s) {
      float om = sM[tid + s]; int oi = sI[tid + s];
      if (om > sM[tid] || (om == sM[tid] && oi < sI[tid])) {
        sM[tid] = om; sI[tid] = oi;
      }
    }
    __syncthreads();
  }
  const float maxv = sM[0];
  const int best = sI[0];
  __syncthreads();

  float se = 0.0f;
  #pragma unroll
  for (int u = 0; u < 32; u++) {
    float e = expf(v[u] - maxv);
    v[u] = e;
    se += e;
  }
  sM[tid] = se;
  __syncthreads();
  for (int s = 128; s > 0; s >>= 1) {
    if (tid < s) sM[tid] += sM[tid + s];
    __syncthreads();
  }
  const float invsum = 1.0f / sM[0];

  float* prow = prob + (size_t)row * N;
  #pragma unroll
  for (int u = 0; u < 32; u++) {
    int col = u * 256 + tid;
    prow[col] = v[u] * invsum;
  }

  // z_q row = emb[best] * inv_norm[best] (exact fp32, matches reference cb)
  const float sc = inv_norm[best];
  const float* erow = emb + (size_t)best * KDIM;
  float* zrow = zq + (size_t)row * KDIM;
  for (int j = tid; j < KDIM; j += 256) zrow[j] = erow[j] * sc;

  if (tid == 0) {
    enc[(size_t)row * N + best] = 1.0f;
    idxout[row] = (float)best;
    atomicAdd(&counts[best], 1);
    float znr = zn[row], cn = cbn[best];
    float dotv = maxv * (znr * cn + 1e-6f);     // recover raw dot from scaled d
    float cosv = dotv / (fmaxf(znr, 1e-8f) * fmaxf(cn, 1e-8f));
    atomicAdd(cos_sum, cosv);
  }
}

// ---------------------------------------------------------------------------
// Kernel 4: scalar finalize — KL, perplexity, loss.
// ---------------------------------------------------------------------------
__global__ __launch_bounds__(256) void finalize_kernel(
    const int* __restrict__ counts, const float* __restrict__ cos_sum,
    float* __restrict__ out) {
  __shared__ float sKL[256];
  __shared__ float sEnt[256];
  const int tid = threadIdx.x;
  float kl = 0.0f, ent = 0.0f;
  for (int i = tid; i < N; i += 256) {
    float e = (float)counts[i] * (1.0f / (float)M);
    kl += e * logf((1.0f / (float)N) / (e + 1e-6f));
    ent += e * logf(e + 1e-6f);
  }
  sKL[tid] = kl; sEnt[tid] = ent;
  __syncthreads();
  for (int s = 128; s > 0; s >>= 1) {
    if (tid < s) { sKL[tid] += sKL[tid + s]; sEnt[tid] += sEnt[tid + s]; }
    __syncthreads();
  }
  if (tid == 0) {
    float mc = *cos_sum * (1.0f / (float)M);
    out[OFF_LOSS] = (1.0f - mc) + 0.25f * (1.0f - mc);
    out[OFF_CONTRASTIVE] = 0.0f;
    out[OFF_KL] = -sKL[0];
    out[OFF_PERP] = expf(-sEnt[0]);
  }
}

extern "C" void kernel_launch(void* const* d_in, const int* in_sizes, int n_in,
                              void* d_out, int out_size, void* d_ws,
                              size_t ws_size, hipStream_t stream) {
  const float* z = (const float*)d_in[0];
  const float* emb = (const float*)d_in[1];
  float* out = (float*)d_out;

  // workspace layout (floats): inv_norm[8192] | cbn[8192] | zn[8192] |
  //                            counts[8192] (int) | cos_sum[1]
  float* wsf = (float*)d_ws;
  float* inv_norm = wsf;
  float* cbn = wsf + 8192;
  float* zn = wsf + 16384;
  int* counts = (int*)(wsf + 24576);
  float* cos_sum = wsf + 24576 + 8192;

  // fp16 hi/lo planes (32 MB) staged in the enc output region; enc is
  // memset AFTER the gemm has consumed them (stream-ordered).
  uintptr_t sb = (uintptr_t)(out + OFF_ENC);
  sb = (sb + 63) & ~(uintptr_t)63;
  _Float16* zhi = (_Float16*)sb;
  _Float16* zlo = zhi + (size_t)M * KDIM;
  _Float16* chi = zlo + (size_t)M * KDIM;
  _Float16* clo = chi + (size_t)N * KDIM;

  hipMemsetAsync(counts, 0, (8192 + 1) * sizeof(float), stream);

  prep_kernel<<<(2 * N) / 4, 256, 0, stream>>>(z, emb, inv_norm, cbn, zn,
                                               zhi, zlo, chi, clo);

  dim3 g2(64, 64);
  gemm_kernel<<<g2, 256, 0, stream>>>(zhi, zlo, chi, clo, zn, cbn,
                                      out + OFF_D);

  // zero the one-hot region only after gemm no longer needs the scratch
  hipMemsetAsync(out + OFF_ENC, 0, (size_t)M * N * sizeof(float), stream);

  row_kernel<<<M, 256, 0, stream>>>(out + OFF_D, out + OFF_PROB, out + OFF_ENC,
                                    out + OFF_ZQ, out + OFF_IDX, emb, inv_norm,
                                    cbn, zn, counts, cos_sum);

  finalize_kernel<<<1, 256, 0, stream>>>(counts, cos_sum, out);
}

// Round 2
// 1112.431 us; speedup vs baseline: 1.4999x; 1.0102x over previous
//
#include <hip/hip_runtime.h>
#include <cstdint>

// Problem constants
#define M 8192          // B*H*W = 32*16*16
#define N 8192          // N_E
#define KDIM 512        // E_DIM

// Output layout (flat float32, reference return order)
static const size_t OFF_LOSS = 0;
static const size_t OFF_CONTRASTIVE = 1;
static const size_t OFF_KL = 2;
static const size_t OFF_PROB = 3;                                   // 8192*8192
static const size_t OFF_D    = OFF_PROB + (size_t)M * N;            // 67108867
static const size_t OFF_ZQ   = OFF_D + (size_t)M * N;               // 134217731
static const size_t OFF_PERP = OFF_ZQ + (size_t)M * KDIM;           // 138412035
static const size_t OFF_ENC  = OFF_PERP + 1;                        // 138412036
static const size_t OFF_IDX  = OFF_ENC + (size_t)M * N;             // 205520900

typedef _Float16 f16x8 __attribute__((ext_vector_type(8)));
typedef float f32x4 __attribute__((ext_vector_type(4)));

// Power-of-two scales keep fp16 lo-planes out of subnormal-flush range.
// Exact (exponent shift only); folded out in the GEMM epilogue.
#define ZSCALE 16.0f     // z ~ N(0,1): |z*16| <~ 100
#define CSCALE 512.0f    // cb entries ~ +-0.08: |cb*512| <~ 50
#define INV_SCALE (1.0f / (16.0f * 512.0f))   // 2^-13, exact

__device__ __forceinline__ void gload16(const void* g, void* l) {
  __builtin_amdgcn_global_load_lds(
      (const __attribute__((address_space(1))) uint32_t*)g,
      (__attribute__((address_space(3))) uint32_t*)l, 16, 0, 0);
}

// ---------------------------------------------------------------------------
// Kernel 1 (prep): row norms + fp16 hi/lo split of scaled inputs.
// One wave per row; rows 0..8191 = emb (-> cb split), 8192..16383 = z.
// ---------------------------------------------------------------------------
__global__ __launch_bounds__(256) void prep_kernel(
    const float* __restrict__ z, const float* __restrict__ emb,
    float* __restrict__ inv_norm, float* __restrict__ cbn,
    float* __restrict__ zn,
    _Float16* __restrict__ zhi, _Float16* __restrict__ zlo,
    _Float16* __restrict__ chi, _Float16* __restrict__ clo) {
  int g = blockIdx.x * 4 + (threadIdx.x >> 6);
  int lane = threadIdx.x & 63;
  if (g < N) {
    const float* p = emb + (size_t)g * KDIM + lane * 8;
    float4 v0 = *(const float4*)p;
    float4 v1 = *(const float4*)(p + 4);
    float s = v0.x * v0.x + v0.y * v0.y + v0.z * v0.z + v0.w * v0.w +
              v1.x * v1.x + v1.y * v1.y + v1.z * v1.z + v1.w * v1.w;
    #pragma unroll
    for (int off = 32; off > 0; off >>= 1) s += __shfl_down(s, off, 64);
    s = __shfl(s, 0, 64);
    float inv = 1.0f / sqrtf(s);
    float c[8] = {v0.x * inv, v0.y * inv, v0.z * inv, v0.w * inv,
                  v1.x * inv, v1.y * inv, v1.z * inv, v1.w * inv};
    float s2 = 0.0f;
    #pragma unroll
    for (int j = 0; j < 8; j++) s2 += c[j] * c[j];
    #pragma unroll
    for (int off = 32; off > 0; off >>= 1) s2 += __shfl_down(s2, off, 64);
    if (lane == 0) { inv_norm[g] = inv; cbn[g] = sqrtf(s2); }
    f16x8 h, l;
    #pragma unroll
    for (int j = 0; j < 8; j++) {
      float cs = c[j] * CSCALE;
      _Float16 hh = (_Float16)cs;
      h[j] = hh;
      l[j] = (_Float16)(cs - (float)hh);
    }
    *(f16x8*)&chi[(size_t)g * KDIM + lane * 8] = h;
    *(f16x8*)&clo[(size_t)g * KDIM + lane * 8] = l;
  } else {
    int r = g - N;
    const float* p = z + (size_t)r * KDIM + lane * 8;
    float4 v0 = *(const float4*)p;
    float4 v1 = *(const float4*)(p + 4);
    float s = v0.x * v0.x + v0.y * v0.y + v0.z * v0.z + v0.w * v0.w +
              v1.x * v1.x + v1.y * v1.y + v1.z * v1.z + v1.w * v1.w;
    #pragma unroll
    for (int off = 32; off > 0; off >>= 1) s += __shfl_down(s, off, 64);
    if (lane == 0) zn[r] = sqrtf(__shfl(s, 0, 64));
    float c[8] = {v0.x, v0.y, v0.z, v0.w, v1.x, v1.y, v1.z, v1.w};
    f16x8 h, l;
    #pragma unroll
    for (int j = 0; j < 8; j++) {
      float cs = c[j] * ZSCALE;
      _Float16 hh = (_Float16)cs;
      h[j] = hh;
      l[j] = (_Float16)(cs - (float)hh);
    }
    *(f16x8*)&zhi[(size_t)r * KDIM + lane * 8] = h;
    *(f16x8*)&zlo[(size_t)r * KDIM + lane * 8] = l;
  }
}

// ---------------------------------------------------------------------------
// Kernel 2: split-fp16 MFMA GEMM (unchanged from round 1; ~763 TF).
//   d[i][j] = (Ah.Bh + Ah.Bl + Al.Bh)[i][j] * 2^-13 / (zn_i*cbn_j + 1e-6)
// ---------------------------------------------------------------------------
__global__ __launch_bounds__(256, 2) void gemm_kernel(
    const _Float16* __restrict__ zhi, const _Float16* __restrict__ zlo,
    const _Float16* __restrict__ chi, const _Float16* __restrict__ clo,
    const float* __restrict__ zn, const float* __restrict__ cbn,
    float* __restrict__ dout) {
  __shared__ __align__(16) _Float16 As[128][64];
  __shared__ __align__(16) _Float16 Bs[128][64];

  const int tid = threadIdx.x;
  const int lane = tid & 63;
  const int wid = tid >> 6;
  const int wr = wid >> 1;
  const int wc = wid & 1;
  const int l15 = lane & 15;
  const int l4 = lane >> 4;

  int bid = blockIdx.y * 64 + blockIdx.x;
  int swz = (bid & 7) * 512 + (bid >> 3);
  const int row0 = (swz >> 6) * 128;
  const int col0 = (swz & 63) * 128;

  const int srow = tid >> 3;
  const int sP = tid & 7;
  const int sL = sP ^ (srow & 7);
  const _Float16* asrc = ((sL & 4) ? zlo : zhi) +
                         (size_t)(row0 + srow) * KDIM + (sL & 3) * 8;
  const _Float16* bsrc = ((sL & 4) ? clo : chi) +
                         (size_t)(col0 + srow) * KDIM + (sL & 3) * 8;
  char* adst = (char*)&As[0][0] + tid * 16;
  char* bdst = (char*)&Bs[0][0] + tid * 16;

  f32x4 acc[4][4];
  #pragma unroll
  for (int i = 0; i < 4; i++)
    #pragma unroll
    for (int j = 0; j < 4; j++)
      #pragma unroll
      for (int q = 0; q < 4; q++) acc[i][j][q] = 0.0f;

  auto stage = [&](int kt) {
    #pragma unroll
    for (int p = 0; p < 4; p++) {
      gload16(asrc + (size_t)p * (32 * KDIM) + kt, adst + p * 4096);
      gload16(bsrc + (size_t)p * (32 * KDIM) + kt, bdst + p * 4096);
    }
  };

  stage(0);
  for (int kt = 0; kt < KDIM; kt += 32) {
    __syncthreads();

    f16x8 ahi[4], alo[4], bhi[4], blo[4];
    #pragma unroll
    for (int i = 0; i < 4; i++) {
      int ra = wr * 64 + i * 16 + l15;
      int xa = ra & 7;
      ahi[i] = *(const f16x8*)&As[ra][(l4 ^ xa) * 8];
      alo[i] = *(const f16x8*)&As[ra][((l4 + 4) ^ xa) * 8];
      int rb = wc * 64 + i * 16 + l15;
      int xb = rb & 7;
      bhi[i] = *(const f16x8*)&Bs[rb][(l4 ^ xb) * 8];
      blo[i] = *(const f16x8*)&Bs[rb][((l4 + 4) ^ xb) * 8];
    }

    __syncthreads();
    if (kt + 32 < KDIM) stage(kt + 32);

    #pragma unroll
    for (int m2 = 0; m2 < 4; m2++)
      #pragma unroll
      for (int n2 = 0; n2 < 4; n2++)
        acc[m2][n2] = __builtin_amdgcn_mfma_f32_16x16x32_f16(
            ahi[m2], bhi[n2], acc[m2][n2], 0, 0, 0);
    #pragma unroll
    for (int m2 = 0; m2 < 4; m2++)
      #pragma unroll
      for (int n2 = 0; n2 < 4; n2++)
        acc[m2][n2] = __builtin_amdgcn_mfma_f32_16x16x32_f16(
            ahi[m2], blo[n2], acc[m2][n2], 0, 0, 0);
    #pragma unroll
    for (int m2 = 0; m2 < 4; m2++)
      #pragma unroll
      for (int n2 = 0; n2 < 4; n2++)
        acc[m2][n2] = __builtin_amdgcn_mfma_f32_16x16x32_f16(
            alo[m2], bhi[n2], acc[m2][n2], 0, 0, 0);
  }

  const int cb0 = col0 + wc * 64 + l15;
  const int rb0 = row0 + wr * 64 + l4 * 4;
  float cw[4];
  #pragma unroll
  for (int n2 = 0; n2 < 4; n2++) cw[n2] = cbn[cb0 + n2 * 16];
  #pragma unroll
  for (int m2 = 0; m2 < 4; m2++) {
    #pragma unroll
    for (int r2 = 0; r2 < 4; r2++) {
      int row = rb0 + m2 * 16 + r2;
      float zr = zn[row];
      size_t o = (size_t)row * N + cb0;
      #pragma unroll
      for (int n2 = 0; n2 < 4; n2++) {
        dout[o + n2 * 16] =
            (acc[m2][n2][r2] * INV_SCALE) / (zr * cw[n2] + 1e-6f);
      }
    }
  }
}

// ---------------------------------------------------------------------------
// Kernel 3: per-row argmax + softmax + one-hot (full row incl. zeros) + z_q +
// histogram + per-row cosine. One 256-thread block per row.
// d/prob are offset ==3 (mod 4 floats); we work on the shifted 16B-aligned
// grid base-3: chunks q=1..2047 are full float4; the 4 stragglers
// (c=0,8189,8190,8191) are masked lanes handled by tid 0. Masked lanes carry
// -1e30 so exp()->0 and they never win argmax.
// ---------------------------------------------------------------------------
__global__ __launch_bounds__(256) void row_kernel(
    const float* __restrict__ dmat, float* __restrict__ prob,
    float* __restrict__ enc, float* __restrict__ zq,
    float* __restrict__ idxout, const float* __restrict__ emb,
    const float* __restrict__ inv_norm, const float* __restrict__ cbn,
    const float* __restrict__ zn, int* __restrict__ counts,
    float* __restrict__ cosrow) {
  const int row = blockIdx.x;
  const int tid = threadIdx.x;
  const float* dbase = dmat + (size_t)row * N - 3;   // 16B-aligned

  float4 v4[8];
  #pragma unroll
  for (int u = 0; u < 8; u++)
    v4[u] = *(const float4*)(dbase + 4 * (u * 256 + tid));
  float4 vb;
  if (tid == 0) {
    vb = *(const float4*)(dbase + 8192);             // c = 8189..8191 + 1 junk
    v4[0].x = -1e30f; v4[0].y = -1e30f; v4[0].z = -1e30f;  // c = -3..-1 junk
    vb.w = -1e30f;
  } else {
    vb = make_float4(-1e30f, -1e30f, -1e30f, -1e30f);
  }

  // per-thread argmax with explicit (value, min-index) ordering
  float m = -1e30f;
  int mi = 0x7fffffff;
  #define UPD(x, c) { float _x = (x); int _c = (c); \
      if (_x > m || (_x == m && _c < mi)) { m = _x; mi = _c; } }
  #pragma unroll
  for (int u = 0; u < 8; u++) {
    int c0 = 4 * (u * 256 + tid) - 3;
    UPD(v4[u].x, c0 + 0); UPD(v4[u].y, c0 + 1);
    UPD(v4[u].z, c0 + 2); UPD(v4[u].w, c0 + 3);
  }
  UPD(vb.x, 8189); UPD(vb.y, 8190); UPD(vb.z, 8191); UPD(vb.w, 0x3fffffff);
  #undef UPD

  // wave reduce (max, min idx)
  #pragma unroll
  for (int off = 32; off > 0; off >>= 1) {
    float om = __shfl_down(m, off, 64);
    int oi = __shfl_down(mi, off, 64);
    if (om > m || (om == m && oi < mi)) { m = om; mi = oi; }
  }
  __shared__ float swm[4];
  __shared__ int swi[4];
  __shared__ float ssum[4];
  if ((tid & 63) == 0) { swm[tid >> 6] = m; swi[tid >> 6] = mi; }
  __syncthreads();
  float maxv = swm[0];
  int best = swi[0];
  #pragma unroll
  for (int w = 1; w < 4; w++) {
    float om = swm[w]; int oi = swi[w];
    if (om > maxv || (om == maxv && oi < best)) { maxv = om; best = oi; }
  }

  // exp in place + sum (masked lanes -> exp(-huge)=0)
  float se = 0.0f;
  #pragma unroll
  for (int u = 0; u < 8; u++) {
    v4[u].x = expf(v4[u].x - maxv); v4[u].y = expf(v4[u].y - maxv);
    v4[u].z = expf(v4[u].z - maxv); v4[u].w = expf(v4[u].w - maxv);
    se += v4[u].x + v4[u].y + v4[u].z + v4[u].w;
  }
  vb.x = expf(vb.x - maxv); vb.y = expf(vb.y - maxv); vb.z = expf(vb.z - maxv);
  se += vb.x + vb.y + vb.z;
  #pragma unroll
  for (int off = 32; off > 0; off >>= 1) se += __shfl_down(se, off, 64);
  if ((tid & 63) == 0) ssum[tid >> 6] = se;
  __syncthreads();
  const float invsum = 1.0f / (ssum[0] + ssum[1] + ssum[2] + ssum[3]);

  // prob stores: vector chunks q=1..2047; stragglers scalar on tid 0
  float* pbase = prob + (size_t)row * N - 3;         // == out+row*N, aligned
  #pragma unroll
  for (int u = 0; u < 8; u++) {
    int q = u * 256 + tid;
    float4 pv = make_float4(v4[u].x * invsum, v4[u].y * invsum,
                            v4[u].z * invsum, v4[u].w * invsum);
    if (q != 0) *(float4*)(pbase + 4 * q) = pv;
  }
  if (tid == 0) {
    float* prow = prob + (size_t)row * N;
    prow[0] = v4[0].w * invsum;
    prow[8189] = vb.x * invsum;
    prow[8190] = vb.y * invsum;
    prow[8191] = vb.z * invsum;
  }

  // enc row: streamed zeros with the one-hot lane composed in-register
  float* ebase = enc + (size_t)row * N;              // aligned
  const int bq = best >> 2, bj = best & 3;
  #pragma unroll
  for (int u = 0; u < 8; u++) {
    int q = u * 256 + tid;
    float4 zv = make_float4(0.0f, 0.0f, 0.0f, 0.0f);
    if (q == bq) {
      zv.x = (bj == 0) ? 1.0f : 0.0f;
      zv.y = (bj == 1) ? 1.0f : 0.0f;
      zv.z = (bj == 2) ? 1.0f : 0.0f;
      zv.w = (bj == 3) ? 1.0f : 0.0f;
    }
    *(float4*)(ebase + 4 * q) = zv;
  }

  // z_q row = emb[best] * inv_norm[best] (exact fp32)
  const float sc = inv_norm[best];
  const float* erow = emb + (size_t)best * KDIM;
  float* zrow = zq + (size_t)row * KDIM;
  for (int j = tid; j < KDIM; j += 256) zrow[j] = erow[j] * sc;

  if (tid == 0) {
    idxout[row] = (float)best;
    atomicAdd(&counts[best], 1);                     // scattered, low contention
    float znr = zn[row], cn = cbn[best];
    float dotv = maxv * (znr * cn + 1e-6f);
    cosrow[row] = dotv / (fmaxf(znr, 1e-8f) * fmaxf(cn, 1e-8f));
  }
}

// ---------------------------------------------------------------------------
// Kernel 4: scalar finalize — KL, perplexity, cos-sum, loss.
// ---------------------------------------------------------------------------
__global__ __launch_bounds__(256) void finalize_kernel(
    const int* __restrict__ counts, const float* __restrict__ cosrow,
    float* __restrict__ out) {
  __shared__ float sKL[256];
  __shared__ float sEnt[256];
  __shared__ float sCos[256];
  const int tid = threadIdx.x;
  float kl = 0.0f, ent = 0.0f;
  for (int i = tid; i < N; i += 256) {
    float e = (float)counts[i] * (1.0f / (float)M);
    kl += e * logf((1.0f / (float)N) / (e + 1e-6f));
    ent += e * logf(e + 1e-6f);
  }
  float cs = 0.0f;
  for (int i = tid; i < M; i += 256) cs += cosrow[i];
  sKL[tid] = kl; sEnt[tid] = ent; sCos[tid] = cs;
  __syncthreads();
  for (int s = 128; s > 0; s >>= 1) {
    if (tid < s) {
      sKL[tid] += sKL[tid + s];
      sEnt[tid] += sEnt[tid + s];
      sCos[tid] += sCos[tid + s];
    }
    __syncthreads();
  }
  if (tid == 0) {
    float mc = sCos[0] * (1.0f / (float)M);
    out[OFF_LOSS] = (1.0f - mc) + 0.25f * (1.0f - mc);
    out[OFF_CONTRASTIVE] = 0.0f;
    out[OFF_KL] = -sKL[0];
    out[OFF_PERP] = expf(-sEnt[0]);
  }
}

extern "C" void kernel_launch(void* const* d_in, const int* in_sizes, int n_in,
                              void* d_out, int out_size, void* d_ws,
                              size_t ws_size, hipStream_t stream) {
  const float* z = (const float*)d_in[0];
  const float* emb = (const float*)d_in[1];
  float* out = (float*)d_out;

  // workspace layout (floats): inv_norm[8192] | cbn[8192] | zn[8192] |
  //                            counts[8192] (int) | cosrow[8192]
  float* wsf = (float*)d_ws;
  float* inv_norm = wsf;
  float* cbn = wsf + 8192;
  float* zn = wsf + 16384;
  int* counts = (int*)(wsf + 24576);
  float* cosrow = wsf + 32768;

  // fp16 hi/lo planes (32 MB) staged in the enc output region; row_kernel
  // overwrites the whole enc region AFTER gemm consumed them (stream order).
  uintptr_t sb = (uintptr_t)(out + OFF_ENC);
  sb = (sb + 63) & ~(uintptr_t)63;
  _Float16* zhi = (_Float16*)sb;
  _Float16* zlo = zhi + (size_t)M * KDIM;
  _Float16* chi = zlo + (size_t)M * KDIM;
  _Float16* clo = chi + (size_t)N * KDIM;

  hipMemsetAsync(counts, 0, 8192 * sizeof(int), stream);

  prep_kernel<<<(2 * N) / 4, 256, 0, stream>>>(z, emb, inv_norm, cbn, zn,
                                               zhi, zlo, chi, clo);

  dim3 g2(64, 64);
  gemm_kernel<<<g2, 256, 0, stream>>>(zhi, zlo, chi, clo, zn, cbn,
                                      out + OFF_D);

  row_kernel<<<M, 256, 0, stream>>>(out + OFF_D, out + OFF_PROB, out + OFF_ENC,
                                    out + OFF_ZQ, out + OFF_IDX, emb, inv_norm,
                                    cbn, zn, counts, cosrow);

  finalize_kernel<<<1, 256, 0, stream>>>(counts, cosrow, out);
}